// Round 8
// baseline (2437.242 us; speedup 1.0000x reference)
//
#include <hip/hip_runtime.h>

typedef __bf16 bf16_t;
typedef __bf16 bf16x8 __attribute__((ext_vector_type(8)));
typedef float  f32x4  __attribute__((ext_vector_type(4)));
typedef unsigned short u16;
typedef unsigned int   u32;

union BF8 { bf16x8 v; uint4 w; };
struct Frag8 { bf16x8 f[8]; };

__device__ __forceinline__ u16 f2bf(float f) {
    union { float f; unsigned u; } v; v.f = f;
    unsigned u = v.u;
    return (u16)((u + 0x7fffu + ((u >> 16) & 1u)) >> 16);  // RNE
}

__device__ __forceinline__ u32 pk(float lo, float hi) {
    u16 a = __builtin_bit_cast(u16, (__bf16)lo);
    u16 b = __builtin_bit_cast(u16, (__bf16)hi);
    return (u32)a | ((u32)b << 16);
}

__device__ __forceinline__ bf16x8 cvt8(const float* __restrict__ p) {
    float4 a = *(const float4*)p;
    float4 b = *(const float4*)(p + 4);
    bf16x8 r;
    r[0] = (__bf16)a.x; r[1] = (__bf16)a.y; r[2] = (__bf16)a.z; r[3] = (__bf16)a.w;
    r[4] = (__bf16)b.x; r[5] = (__bf16)b.y; r[6] = (__bf16)b.z; r[7] = (__bf16)b.w;
    return r;
}

// ---- prep: W1 [256x128] -> W1t [128x256] bf16 (transposed); W2 -> W2t [128x128]
__global__ __launch_bounds__(256) void prep_weights(
    const float* __restrict__ W1, const float* __restrict__ W2,
    u16* __restrict__ W1t, u16* __restrict__ W2t)
{
    int tid = blockIdx.x * 256 + threadIdx.x;
    if (tid < 128 * 256) {
        int n = tid >> 8, k = tid & 255;
        W1t[tid] = f2bf(W1[k * 128 + n]);
    } else if (tid < 128 * 256 + 128 * 128) {
        int t = tid - 128 * 256;
        int n = t >> 7, k = t & 127;
        W2t[t] = f2bf(W2[k * 128 + n]);
    }
}

// ---- prep: cast x, u to bf16
__global__ __launch_bounds__(256) void prep_cast(
    const float* __restrict__ x, const float* __restrict__ u,
    bf16_t* __restrict__ xb, bf16_t* __restrict__ ub, int nx, int nu)
{
    int total = (nx + nu) >> 2;
    for (int i = blockIdx.x * 256 + threadIdx.x; i < total; i += gridDim.x * 256) {
        int j = i << 2;
        const float* src; bf16_t* dst;
        if (j < nx) { src = x + j;        dst = xb + j; }
        else        { src = u + (j - nx); dst = ub + (j - nx); }
        float4 v = *(const float4*)src;
        dst[0] = (__bf16)v.x; dst[1] = (__bf16)v.y;
        dst[2] = (__bf16)v.z; dst[3] = (__bf16)v.w;
    }
}

// ---- prep: resolve (sender r, receiver c, group g=batch[r]) per edge
__global__ __launch_bounds__(256) void prep_rcg(
    const int* __restrict__ ei, const int* __restrict__ batch,
    int4* __restrict__ rcg, int E)
{
    int i = blockIdx.x * 256 + threadIdx.x;
    if (i < E) {
        int r = ei[i], c = ei[E + i];
        rcg[i] = make_int4(r, c, batch[r], 0);
    }
}

// Persistent blocks: 1024 thr (16 waves, 1 block/CU), weights in LDS once.
// Per wave-tile: 16 edges. Pipeline: GEMM1(t) -> transpose -> gather(t+S) -> GEMM2(t).
// MODE: 2 = precast + rcg, 1 = precast only, 0 = raw
template<int MODE>
__global__ __launch_bounds__(1024, 4) void edge_mlp(
    const float* __restrict__ x, const float* __restrict__ e, const float* __restrict__ u,
    const bf16_t* __restrict__ xb, const bf16_t* __restrict__ ub,
    const float* __restrict__ b1, const float* __restrict__ b2,
    const float* __restrict__ ln_g, const float* __restrict__ ln_b,
    const int* __restrict__ ei, const int* __restrict__ batch,
    const int4* __restrict__ rcg,
    const u16* __restrict__ W1t, const u16* __restrict__ W2t,
    float* __restrict__ out, int E)
{
    __shared__ __align__(16) u16 sW1[128 * 256];   // 64KB, rows 512B, XOR-swizzled
    __shared__ __align__(16) u16 sW2[128 * 128];   // 32KB, rows 256B, XOR-swizzled
    __shared__ __align__(16) float sP[512];        // b1 | b2 | ln_g | ln_b

    const int tid = threadIdx.x;
    #pragma unroll
    for (int i = 0; i < 4; ++i) {
        int byte = (i * 1024 + tid) * 16;
        int row  = byte >> 9;
        *(uint4*)((char*)sW1 + (byte ^ ((row & 7) << 4))) =
            *(const uint4*)((const char*)W1t + byte);
    }
    #pragma unroll
    for (int i = 0; i < 2; ++i) {
        int byte = (i * 1024 + tid) * 16;
        int row  = byte >> 8;
        *(uint4*)((char*)sW2 + (byte ^ ((row & 7) << 4))) =
            *(const uint4*)((const char*)W2t + byte);
    }
    if (tid < 128) {
        sP[tid]       = b1[tid];   sP[128 + tid] = b2[tid];
        sP[256 + tid] = ln_g[tid]; sP[384 + tid] = ln_b[tid];
    }
    __syncthreads();
    // no further block barriers — waves fully independent

    const int wave = tid >> 6, lane = tid & 63;
    const int lrow = lane & 15, kg = lane >> 4;
    const int swz  = (lrow & 7) << 4;              // lane-constant LDS XOR
    const int NT = (E + 15) >> 4;
    const int STRIDE = gridDim.x * 16;
    int wt = blockIdx.x * 16 + wave;
    if (wt >= NT) return;

    auto ldidx = [&](int t) -> int4 {
        int eid = t * 16 + lrow; eid = eid < E ? eid : E - 1;
        if constexpr (MODE == 2) { int4 r = rcg[eid]; r.w = eid; return r; }
        else {
            int4 r; r.x = ei[eid]; r.y = ei[E + eid]; r.z = batch[r.x]; r.w = eid;
            return r;
        }
    };
    auto gather = [&](int4 ix) -> Frag8 {
        Frag8 g;
        const float* ep = e + (size_t)ix.w * 64;
        #pragma unroll
        for (int q = 0; q < 2; ++q) {
            int off = q * 32 + kg * 8;
            g.f[q] = cvt8(ep + off);
            if constexpr (MODE >= 1) {
                g.f[2 + q] = *(const bf16x8*)(xb + (size_t)ix.y * 64 + off);  // receiver
                g.f[4 + q] = *(const bf16x8*)(xb + (size_t)ix.x * 64 + off);  // sender
                g.f[6 + q] = *(const bf16x8*)(ub + (size_t)ix.z * 64 + off);  // global
            } else {
                g.f[2 + q] = cvt8(x + (size_t)ix.y * 64 + off);
                g.f[4 + q] = cvt8(x + (size_t)ix.x * 64 + off);
                g.f[6 + q] = cvt8(u + (size_t)ix.z * 64 + off);
            }
        }
        return g;
    };

    // preheader: indices + gathers for first tile
    int4  iN = ldidx(wt);
    Frag8 g  = gather(iN);
    {
        int nwt = wt + STRIDE; nwt = nwt < NT ? nwt : wt;
        iN = ldidx(nwt);                           // in flight during first GEMM1
    }

    for (; wt < NT; wt += STRIDE) {
        const long tb = (long)wt * 16;

        // ---- GEMM1 (swapped): D[h][edge] = W1 rows x attr cols
        f32x4 a1[8] = {};
        #pragma unroll
        for (int kk = 0; kk < 8; ++kk) {
            #pragma unroll
            for (int mt = 0; mt < 8; ++mt) {
                int byte = ((mt * 16 + lrow) << 9) + (kk << 6) + (kg << 4);
                bf16x8 wf = *(const bf16x8*)((const char*)sW1 + (byte ^ swz));
                a1[mt] = __builtin_amdgcn_mfma_f32_16x16x32_bf16(wf, g.f[kk], a1[mt], 0, 0, 0);
            }
        }

        // ---- bias1 + relu (h = mt*16 + kg*4 + r)
        #pragma unroll
        for (int mt = 0; mt < 8; ++mt) {
            float4 bv = *(const float4*)(sP + mt * 16 + kg * 4);
            #pragma unroll
            for (int r = 0; r < 4; ++r) {
                float v = a1[mt][r] + (&bv.x)[r];
                a1[mt][r] = v > 0.f ? v : 0.f;
            }
        }

        // ---- in-register transpose: lane needs h = kk*32 + kg*8 + j (j=0..7)
        // source lane kg' = (kg&1)*2 + (j>>2), value from mt = kk*2 + (kg>>1), r = j&3.
        // NOTE: shuffle BOTH mt candidates, select at DESTINATION (select-inside-shuffle
        // is evaluated on the source lane and routes half the lanes wrong).
        const int src_lo = ((kg & 1) * 2) * 16 + lrow;
        const int src_hi = src_lo + 16;
        const bool hi = kg >= 2;                   // mt parity this lane needs
        bf16x8 pfr[4];
        #pragma unroll
        for (int kk = 0; kk < 4; ++kk) {
            u32 A0 = pk(a1[kk * 2][0],     a1[kk * 2][1]);
            u32 A1 = pk(a1[kk * 2][2],     a1[kk * 2][3]);
            u32 B0 = pk(a1[kk * 2 + 1][0], a1[kk * 2 + 1][1]);
            u32 B1 = pk(a1[kk * 2 + 1][2], a1[kk * 2 + 1][3]);
            u32 tA0 = (u32)__shfl((int)A0, src_lo, 64);
            u32 tA1 = (u32)__shfl((int)A1, src_lo, 64);
            u32 tA2 = (u32)__shfl((int)A0, src_hi, 64);
            u32 tA3 = (u32)__shfl((int)A1, src_hi, 64);
            u32 tB0 = (u32)__shfl((int)B0, src_lo, 64);
            u32 tB1 = (u32)__shfl((int)B1, src_lo, 64);
            u32 tB2 = (u32)__shfl((int)B0, src_hi, 64);
            u32 tB3 = (u32)__shfl((int)B1, src_hi, 64);
            BF8 t;
            t.w = make_uint4(hi ? tB0 : tA0, hi ? tB1 : tA1,
                             hi ? tB2 : tA2, hi ? tB3 : tA3);
            pfr[kk] = t.v;
        }

        // ---- issue next tile's gathers (indices already in flight) + next indices
        g = gather(iN);
        {
            int nwt = wt + 2 * STRIDE; nwt = nwt < NT ? nwt : wt;
            iN = ldidx(nwt);
        }

        // ---- GEMM2 (swapped): D[o][edge] = W2 rows x h cols
        f32x4 a2[8] = {};
        #pragma unroll
        for (int kk = 0; kk < 4; ++kk) {
            #pragma unroll
            for (int mt = 0; mt < 8; ++mt) {
                int byte = ((mt * 16 + lrow) << 8) + (kk << 6) + (kg << 4);
                bf16x8 wf = *(const bf16x8*)((const char*)sW2 + (byte ^ swz));
                a2[mt] = __builtin_amdgcn_mfma_f32_16x16x32_bf16(wf, pfr[kk], a2[mt], 0, 0, 0);
            }
        }

        // ---- bias2 + relu + layernorm (2 shuffles) + float4 stores
        float s = 0.f, s2 = 0.f;
        #pragma unroll
        for (int mt = 0; mt < 8; ++mt) {
            float4 bv = *(const float4*)(sP + 128 + mt * 16 + kg * 4);
            #pragma unroll
            for (int r = 0; r < 4; ++r) {
                float v = a2[mt][r] + (&bv.x)[r];
                v = v > 0.f ? v : 0.f;
                a2[mt][r] = v; s += v; s2 += v * v;
            }
        }
        s  += __shfl_xor(s, 16, 64);  s  += __shfl_xor(s, 32, 64);
        s2 += __shfl_xor(s2, 16, 64); s2 += __shfl_xor(s2, 32, 64);
        float mu   = s * (1.f / 128.f);
        float rstd = rsqrtf(s2 * (1.f / 128.f) - mu * mu + 1e-5f);

        long edge = tb + lrow;
        if (edge < E) {
            float* orow = out + (size_t)edge * 128;
            #pragma unroll
            for (int mt = 0; mt < 8; ++mt) {
                float4 gv = *(const float4*)(sP + 256 + mt * 16 + kg * 4);
                float4 bv = *(const float4*)(sP + 384 + mt * 16 + kg * 4);
                float4 o;
                o.x = (a2[mt][0] - mu) * rstd * gv.x + bv.x;
                o.y = (a2[mt][1] - mu) * rstd * gv.y + bv.y;
                o.z = (a2[mt][2] - mu) * rstd * gv.z + bv.z;
                o.w = (a2[mt][3] - mu) * rstd * gv.w + bv.w;
                *(float4*)(orow + mt * 16 + kg * 4) = o;
            }
        }
    }
}

extern "C" void kernel_launch(void* const* d_in, const int* in_sizes, int n_in,
                              void* d_out, int out_size, void* d_ws, size_t ws_size,
                              hipStream_t stream) {
    const float* x    = (const float*)d_in[0];
    const float* e    = (const float*)d_in[1];
    const float* u    = (const float*)d_in[2];
    const float* W1   = (const float*)d_in[3];
    const float* b1   = (const float*)d_in[4];
    const float* W2   = (const float*)d_in[5];
    const float* b2   = (const float*)d_in[6];
    const float* ln_g = (const float*)d_in[7];
    const float* ln_b = (const float*)d_in[8];
    const int*   ei   = (const int*)d_in[9];
    const int*   batch= (const int*)d_in[10];

    const int E  = in_sizes[9] / 2;
    const int nx = in_sizes[0];
    const int nu = in_sizes[2];

    u16* W1t = (u16*)d_ws;                            // 64KB
    u16* W2t = W1t + 128 * 256;                       // 32KB
    bf16_t* xbp = (bf16_t*)(W2t + 128 * 128);
    bf16_t* ubp = xbp + nx;
    unsigned long long rp = (unsigned long long)(ubp + nu);
    rp = (rp + 15ull) & ~15ull;                       // 16B-align rcg
    int4* rcg = (int4*)rp;

    const size_t base = 98304;
    const size_t xu   = (size_t)(nx + nu) * 2;
    int mode = 0;
    if      (ws_size >= base + xu + 16 + (size_t)E * 16) mode = 2;
    else if (ws_size >= base + xu)                       mode = 1;

    prep_weights<<<192, 256, 0, stream>>>(W1, W2, W1t, W2t);
    if (mode >= 1) {
        int cgrid = ((nx + nu) / 4 + 255) / 256;
        if (cgrid > 2048) cgrid = 2048;
        prep_cast<<<cgrid, 256, 0, stream>>>(x, u, xbp, ubp, nx, nu);
    }
    if (mode == 2)
        prep_rcg<<<(E + 255) / 256, 256, 0, stream>>>(ei, batch, rcg, E);

    dim3 grid(256), blk(1024);
    if (mode == 2)
        edge_mlp<2><<<grid, blk, 0, stream>>>(x, e, u, xbp, ubp, b1, b2, ln_g, ln_b,
                                              ei, batch, rcg,
                                              W1t, W2t, (float*)d_out, E);
    else if (mode == 1)
        edge_mlp<1><<<grid, blk, 0, stream>>>(x, e, u, xbp, ubp, b1, b2, ln_g, ln_b,
                                              ei, batch, nullptr,
                                              W1t, W2t, (float*)d_out, E);
    else
        edge_mlp<0><<<grid, blk, 0, stream>>>(x, e, u, nullptr, nullptr, b1, b2, ln_g, ln_b,
                                              ei, batch, nullptr,
                                              W1t, W2t, (float*)d_out, E);
}